// Round 3
// baseline (213.439 us; speedup 1.0000x reference)
//
#include <hip/hip_runtime.h>
#include <hip/hip_bf16.h>

#define BB 2
#define CC 128
#define HH 48
#define WW 160
#define DD 96
#define HWp (HH*WW)     // 7680
#define CIN 224         // C + D
#define NKC 63          // 2016 / 32 K-chunks

typedef __bf16 bf16_t;
typedef __bf16 bf16x8 __attribute__((ext_vector_type(8)));
typedef float  f32x4  __attribute__((ext_vector_type(4)));
typedef float  f32x2  __attribute__((ext_vector_type(2)));

union ABFrag { uint4 u; bf16x8 v; };
union PackW  { bf16_t h[8]; uint4 u; };
union F4     { float4 f; f32x2 h[2]; };

// ---------------------------------------------------------------------------
// Transpose NCHW -> channel-last. z = 0,1: current (also writes bf16 catT
// channels 0..127); z = 2,3: lookup.
// ---------------------------------------------------------------------------
__global__ __launch_bounds__(256) void k_transpose(
    const float* __restrict__ cur, const float* __restrict__ look,
    float* __restrict__ curT, float* __restrict__ lookT,
    bf16_t* __restrict__ catT) {
  __shared__ float tile[CC * 65];
  int z = blockIdx.y;
  int bIdx = z & 1;
  bool isCur = (z < 2);
  const float* src = (isCur ? cur : look) + (size_t)bIdx * CC * HWp;
  int p0 = blockIdx.x * 64;
  int tid = threadIdx.x;
  int px = tid & 63, cb = tid >> 6;
  #pragma unroll
  for (int k = 0; k < 32; k++) {
    int c = k * 4 + cb;
    tile[c * 65 + px] = src[(size_t)c * HWp + p0 + px];
  }
  __syncthreads();
  int ci = tid & 127, pb = tid >> 7;
  #pragma unroll
  for (int k = 0; k < 32; k++) {
    int pp = k * 2 + pb;
    float v = tile[ci * 65 + pp];
    size_t pix = (size_t)bIdx * HWp + p0 + pp;
    if (isCur) {
      curT[pix * CC + ci] = v;
      catT[pix * CIN + ci] = (bf16_t)v;
    } else {
      lookT[pix * CC + ci] = v;
    }
  }
}

// ---------------------------------------------------------------------------
// Pack conv_w into MFMA B-fragment order (bf16).
// ---------------------------------------------------------------------------
__global__ void k_wpack(const float* __restrict__ cw, bf16_t* __restrict__ wPack) {
  int t = blockIdx.x * 256 + threadIdx.x;
  if (t >= 8 * NKC * 64) return;
  int lane = t & 63;
  int kc = (t >> 6) % NKC;
  int nt = t / (NKC * 64);
  int co = nt * 16 + (lane & 15);
  int kbase = kc * 32 + (lane >> 4) * 8;
  PackW tmp;
  #pragma unroll
  for (int j = 0; j < 8; j++) {
    int kk = kbase + j;
    int tap = kk / 224, ci2 = kk % 224;
    int ky = tap / 3, kx = tap % 3;
    tmp.h[j] = (bf16_t)cw[(((size_t)co * 224 + ci2) * 3 + ky) * 3 + kx];
  }
  *(uint4*)(wPack + (size_t)t * 8) = tmp.u;
}

// ---------------------------------------------------------------------------
// Fused plane-sweep cost. Block = 256 thr = 4 waves over the SAME 8 pixels;
// wave wv covers depths [wv*24, wv*24+24). Within a wave: 8 lanes per pixel,
// 16 channels per lane (4 float4 chunks at stride 32 ch). Packed-fp32 math.
// 7680 waves total (30/CU) to cover L1/L2 load latency.
// ---------------------------------------------------------------------------
__global__ __launch_bounds__(256) void k_cost(
    const float* __restrict__ curT, const float* __restrict__ lookT,
    const float* __restrict__ poses, const float* __restrict__ Kmat,
    const float* __restrict__ invK,
    bf16_t* __restrict__ catT, float* __restrict__ outLow,
    float* __restrict__ outConf) {
  __shared__ float costL[8 * 100];    // stride 100 breaks phase-2 conflicts
  __shared__ float maxL[4][8];
  __shared__ int   cntL[4][8];
  __shared__ __align__(4) bf16_t fillL[8 * 96];

  int tid = threadIdx.x;
  int b = blockIdx.y;
  int wv = tid >> 6;
  int lane = tid & 63;
  int pix = lane >> 3;
  int l = lane & 7;
  int p = blockIdx.x * 8 + pix;
  int hh = p / WW, ww = p % WW;

  const float* Kb  = Kmat + b * 16;
  const float* Tb  = poses + b * 16;   // F = 1
  const float* iKb = invK + b * 16;
  float P[3][4];
  #pragma unroll
  for (int i = 0; i < 3; i++)
    #pragma unroll
    for (int j = 0; j < 4; j++)
      P[i][j] = Kb[i*4+0]*Tb[0*4+j] + Kb[i*4+1]*Tb[1*4+j]
              + Kb[i*4+2]*Tb[2*4+j] + Kb[i*4+3]*Tb[3*4+j];
  float psum = 0.0f;
  #pragma unroll
  for (int i = 0; i < 16; i++) psum += Tb[i];
  bool vpnz = (psum != 0.0f);

  float x = (float)ww, y = (float)hh;
  float cam0 = iKb[0]*x + iKb[1]*y + iKb[2];
  float cam1 = iKb[4]*x + iKb[5]*y + iKb[6];
  float cam2 = iKb[8]*x + iKb[9]*y + iKb[10];
  // projection is linear in depth: c = depth*q + p3
  float qx = P[0][0]*cam0 + P[0][1]*cam1 + P[0][2]*cam2;
  float qy = P[1][0]*cam0 + P[1][1]*cam1 + P[1][2]*cam2;
  float qz = P[2][0]*cam0 + P[2][1]*cam1 + P[2][2]*cam2;
  float px3 = P[0][3], py3 = P[1][3], pz3 = P[2][3];
  bool interior = (hh >= 2 && hh <= HH-3 && ww >= 2 && ww <= WW-3);
  bool groupValid = interior && vpnz;

  // negated current features: 16 ch/lane = 4 chunks at stride 32 channels
  int l4 = l * 4;
  const float* curp = curT + ((size_t)b * HWp + p) * CC + l4;
  F4 negCur[4];
  #pragma unroll
  for (int s4 = 0; s4 < 4; s4++) {
    F4 t; t.f = *(const float4*)(curp + s4 * 32);
    negCur[s4].h[0] = -t.h[0];
    negCur[s4].h[1] = -t.h[1];
  }
  const float* lookB = lookT + (size_t)b * HWp * CC;
  const float stepd = (20.0f - 0.1f) / 95.0f;

  float maxc = 0.0f;
  int cnt = 0;
  for (int dd = 0; dd < 24; dd++) {
    int d = wv * 24 + dd;
    float depth = 0.1f + (float)d * stepd;
    float s = 0.0f;
    if (groupValid) {
      float cxx = fmaf(depth, qx, px3);
      float cyy = fmaf(depth, qy, py3);
      float czz = fmaf(depth, qz, pz3);
      float r = __builtin_amdgcn_rcpf(czz + 1e-7f);
      float gx = cxx * r, gy = cyy * r;
      if (gx >= 2.0f && gx <= (float)(WW-2) && gy >= 2.0f && gy <= (float)(HH-2)) {
        float xf = floorf(gx), yf = floorf(gy);
        float wx = gx - xf, wy = gy - yf;
        int x0 = (int)xf, y0 = (int)yf;
        const float* bp0 = lookB + ((y0 * WW + x0) * CC + l4);
        const float* bp1 = bp0 + WW * CC;
        F4 v00[4], v10[4], v01[4], v11[4];
        #pragma unroll
        for (int s4 = 0; s4 < 4; s4++) {
          v00[s4].f = *(const float4*)(bp0 + s4 * 32);
          v10[s4].f = *(const float4*)(bp0 + s4 * 32 + CC);
          v01[s4].f = *(const float4*)(bp1 + s4 * 32);
          v11[s4].f = *(const float4*)(bp1 + s4 * 32 + CC);
        }
        float w11v = wx * wy;
        float w10v = wx - w11v, w01v = wy - w11v;
        float w00v = 1.0f - wx - wy + w11v;
        f32x2 W00 = {w00v, w00v}, W10 = {w10v, w10v};
        f32x2 W01 = {w01v, w01v}, W11 = {w11v, w11v};
        f32x2 accA = {0.f, 0.f}, accB = {0.f, 0.f};
        #pragma unroll
        for (int s4 = 0; s4 < 4; s4++) {
          #pragma unroll
          for (int hf = 0; hf < 2; hf++) {
            f32x2 t = negCur[s4].h[hf];
            t = __builtin_elementwise_fma(W00, v00[s4].h[hf], t);
            t = __builtin_elementwise_fma(W10, v10[s4].h[hf], t);
            t = __builtin_elementwise_fma(W01, v01[s4].h[hf], t);
            t = __builtin_elementwise_fma(W11, v11[s4].h[hf], t);
            f32x2 a = __builtin_elementwise_max(t, -t);   // v_pk_max with neg mod
            if (s4 & 1) accB += a; else accA += a;
          }
        }
        f32x2 accT = accA + accB;
        s = accT.x + accT.y;
        s += __shfl_xor(s, 1, 8);
        s += __shfl_xor(s, 2, 8);
        s += __shfl_xor(s, 4, 8);
        s *= (1.0f / 128.0f / (1.0f + 1e-7f));
        cnt++;
        if (s > maxc) maxc = s;
      }
    }
    if (l == (d & 7)) costL[pix * 100 + d] = s;
  }
  if (l == 0) { cntL[wv][pix] = cnt; maxL[wv][pix] = maxc; }
  __syncthreads();

  // phase 2: fill/viz/argmin/write — 32 threads per pixel, 3 depths each
  int pix2 = tid >> 5, g = tid & 31;
  int p2 = blockIdx.x * 8 + pix2;
  float m0 = fmaxf(fmaxf(maxL[0][pix2], maxL[1][pix2]),
                   fmaxf(maxL[2][pix2], maxL[3][pix2]));
  int ct = cntL[0][pix2] + cntL[1][pix2] + cntL[2][pix2] + cntL[3][pix2];
  float confF = (ct == DD) ? 1.0f : 0.0f;
  float minv = 3.4e38f;
  int mind = 0x7fffffff;
  #pragma unroll
  for (int k = 0; k < 3; k++) {
    int d = g + 32 * k;
    float c = costL[pix2 * 100 + d];
    float filled = (c == 0.0f) ? m0 : c;
    float viz = (filled == 0.0f) ? 100.0f : filled;
    if (viz < minv) { minv = viz; mind = d; }     // per-thread d ascending
    fillL[pix2 * 96 + d] = (bf16_t)(filled * confF);
  }
  #pragma unroll
  for (int off = 1; off < 32; off <<= 1) {
    float ov = __shfl_xor(minv, off, 32);
    int   oi = __shfl_xor(mind, off, 32);
    if (ov < minv || (ov == minv && oi < mind)) { minv = ov; mind = oi; }
  }
  if (g == 0) {
    outLow[(size_t)b * HWp + p2] = 1.0f / (0.1f + (float)mind * stepd);
    outConf[(size_t)b * HWp + p2] = confF;
  }
  __syncthreads();
  // vectorized bf16 cat write: 48 dwords per pixel
  const unsigned* fu = (const unsigned*)fillL;
  unsigned* cu = (unsigned*)(catT + ((size_t)b * HWp + p2) * CIN + CC);
  #pragma unroll
  for (int k = 0; k < 2; k++) {
    int idx = g + 32 * k;
    if (idx < 48) cu[idx] = fu[pix2 * 48 + idx];
  }
}

// ---------------------------------------------------------------------------
// Implicit-GEMM conv. Each wave: one 16-pixel tile x 16 out-channels (1 nt).
// Block's 4 waves share the SAME nt (identical B stream -> L1 reuse),
// different pixel tiles. 7680 waves total (30/CU).
// ---------------------------------------------------------------------------
__global__ __launch_bounds__(256) void k_conv(
    const bf16_t* __restrict__ catT, const bf16_t* __restrict__ wPack,
    const float* __restrict__ bias, float* __restrict__ out) {
  int wave = threadIdx.x >> 6;
  int lane = threadIdx.x & 63;
  int m16 = lane & 15, quad = lane >> 4;
  int tile = blockIdx.x * 4 + wave;
  int nt = blockIdx.y;
  int P0 = tile * 16;
  int b = P0 / HWp;
  int rp = P0 % HWp;
  int h = rp / WW, w0 = rp % WW;

  f32x4 acc = {0.f, 0.f, 0.f, 0.f};

  #pragma unroll
  for (int tap = 0; tap < 9; tap++) {
    int dy = tap / 3 - 1, dx = tap % 3 - 1;
    int h2 = h + dy;
    int w2 = w0 + m16 + dx;
    bool valid = (h2 >= 0 && h2 < HH && w2 >= 0 && w2 < WW);
    const bf16_t* ap = catT + (ptrdiff_t)((b * HH + h2) * WW + w2) * CIN + quad * 8;
    #pragma unroll
    for (int sub = 0; sub < 7; sub++) {
      ABFrag a;
      if (valid) a.u = *(const uint4*)(ap + sub * 32);
      else       a.u = make_uint4(0u, 0u, 0u, 0u);
      int kc = tap * 7 + sub;
      ABFrag bb;
      bb.u = *(const uint4*)(wPack + (((size_t)nt * NKC + kc) * 64 + lane) * 8);
      acc = __builtin_amdgcn_mfma_f32_16x16x32_bf16(a.v, bb.v, acc, 0, 0, 0);
    }
  }
  // C/D layout: n = lane&15, m = quad*4 + r
  int co = nt * 16 + m16;
  float bi = bias[co];
  #pragma unroll
  for (int r = 0; r < 4; r++) {
    int wloc = w0 + quad * 4 + r;
    float v = acc[r] + bi;
    v = v > 0.0f ? v : 0.0f;
    out[(((size_t)b * CC + co) * HH + h) * WW + wloc] = v;
  }
}

// ---------------------------------------------------------------------------
extern "C" void kernel_launch(void* const* d_in, const int* in_sizes, int n_in,
                              void* d_out, int out_size, void* d_ws, size_t ws_size,
                              hipStream_t stream) {
  const float* cur   = (const float*)d_in[0];
  const float* look  = (const float*)d_in[1];
  const float* poses = (const float*)d_in[2];
  const float* Km    = (const float*)d_in[3];
  const float* iK    = (const float*)d_in[4];
  const float* cw    = (const float*)d_in[5];
  const float* cb    = (const float*)d_in[6];

  float* out     = (float*)d_out;
  float* outLow  = out + (size_t)BB * CC * HWp;
  float* outConf = outLow + (size_t)BB * HWp;

  char* ws = (char*)d_ws;
  float*  curT  = (float*)ws;                                   // 7,864,320 B
  float*  lookT = (float*)(ws + 7864320);                       // 7,864,320 B
  bf16_t* catT  = (bf16_t*)(ws + 2 * 7864320);                  // 6,881,280 B
  bf16_t* wPack = (bf16_t*)(ws + 2 * 7864320 + 6881280);        //   516,096 B

  k_wpack<<<126, 256, 0, stream>>>(cw, wPack);
  k_transpose<<<dim3(120, 4), 256, 0, stream>>>(cur, look, curT, lookT, catT);
  k_cost<<<dim3(960, 2), 256, 0, stream>>>(curT, lookT, poses, Km, iK,
                                           catT, outLow, outConf);
  k_conv<<<dim3(240, 8), 256, 0, stream>>>(catT, wPack, cb, out);
}

// Round 4
// 203.742 us; speedup vs baseline: 1.0476x; 1.0476x over previous
//
#include <hip/hip_runtime.h>
#include <hip/hip_bf16.h>

#define BB 2
#define CC 128
#define HH 48
#define WW 160
#define DD 96
#define HWp (HH*WW)     // 7680
#define CIN 224         // C + D
#define NKC 63          // 2016 / 32 K-chunks

typedef __bf16 bf16_t;
typedef __bf16 bf16x8 __attribute__((ext_vector_type(8)));
typedef float  f32x4  __attribute__((ext_vector_type(4)));
typedef float  f32x2  __attribute__((ext_vector_type(2)));

union ABFrag { uint4 u; bf16x8 v; };
union PackW  { bf16_t h[8]; uint4 u; };
union F4     { float4 f; f32x2 h[2]; };

// ---------------------------------------------------------------------------
// Prep: y = 0..3 -> NCHW->channel-last transpose (cur/look x batch);
//       y = 4   -> conv_w pack into MFMA B-fragment order (grid-stride).
// ---------------------------------------------------------------------------
__global__ __launch_bounds__(256) void k_prep(
    const float* __restrict__ cur, const float* __restrict__ look,
    const float* __restrict__ cw,
    float* __restrict__ curT, float* __restrict__ lookT,
    bf16_t* __restrict__ catT, bf16_t* __restrict__ wPack) {
  int z = blockIdx.y;
  if (z < 4) {
    __shared__ float tile[CC * 65];
    int bIdx = z & 1;
    bool isCur = (z < 2);
    const float* src = (isCur ? cur : look) + (size_t)bIdx * CC * HWp;
    int p0 = blockIdx.x * 64;
    int tid = threadIdx.x;
    int px = tid & 63, cb = tid >> 6;
    #pragma unroll
    for (int k = 0; k < 32; k++) {
      int c = k * 4 + cb;
      tile[c * 65 + px] = src[(size_t)c * HWp + p0 + px];
    }
    __syncthreads();
    int ci = tid & 127, pb = tid >> 7;
    #pragma unroll
    for (int k = 0; k < 32; k++) {
      int pp = k * 2 + pb;
      float v = tile[ci * 65 + pp];
      size_t pix = (size_t)bIdx * HWp + p0 + pp;
      if (isCur) {
        curT[pix * CC + ci] = v;
        catT[pix * CIN + ci] = (bf16_t)v;
      } else {
        lookT[pix * CC + ci] = v;
      }
    }
  } else {
    for (int t = blockIdx.x * 256 + threadIdx.x; t < 8 * NKC * 64; t += 120 * 256) {
      int lane = t & 63;
      int kc = (t >> 6) % NKC;
      int nt = t / (NKC * 64);
      int co = nt * 16 + (lane & 15);
      int kbase = kc * 32 + (lane >> 4) * 8;
      PackW tmp;
      #pragma unroll
      for (int j = 0; j < 8; j++) {
        int kk = kbase + j;
        int tap = kk / 224, ci2 = kk % 224;
        int ky = tap / 3, kx = tap % 3;
        tmp.h[j] = (bf16_t)cw[(((size_t)co * 224 + ci2) * 3 + ky) * 3 + kx];
      }
      *(uint4*)(wPack + (size_t)t * 8) = tmp.u;
    }
  }
}

// ---------------------------------------------------------------------------
// Fused plane-sweep cost (unchanged from R3 — control). Block = 256 thr =
// 4 waves over the SAME 8 pixels; wave wv covers 24 depths. 8 lanes/pixel,
// 16 ch/lane, packed-fp32 math.
// ---------------------------------------------------------------------------
__global__ __launch_bounds__(256) void k_cost(
    const float* __restrict__ curT, const float* __restrict__ lookT,
    const float* __restrict__ poses, const float* __restrict__ Kmat,
    const float* __restrict__ invK,
    bf16_t* __restrict__ catT, float* __restrict__ outLow,
    float* __restrict__ outConf) {
  __shared__ float costL[8 * 100];
  __shared__ float maxL[4][8];
  __shared__ int   cntL[4][8];
  __shared__ __align__(4) bf16_t fillL[8 * 96];

  int tid = threadIdx.x;
  int b = blockIdx.y;
  int wv = tid >> 6;
  int lane = tid & 63;
  int pix = lane >> 3;
  int l = lane & 7;
  int p = blockIdx.x * 8 + pix;
  int hh = p / WW, ww = p % WW;

  const float* Kb  = Kmat + b * 16;
  const float* Tb  = poses + b * 16;   // F = 1
  const float* iKb = invK + b * 16;
  float P[3][4];
  #pragma unroll
  for (int i = 0; i < 3; i++)
    #pragma unroll
    for (int j = 0; j < 4; j++)
      P[i][j] = Kb[i*4+0]*Tb[0*4+j] + Kb[i*4+1]*Tb[1*4+j]
              + Kb[i*4+2]*Tb[2*4+j] + Kb[i*4+3]*Tb[3*4+j];
  float psum = 0.0f;
  #pragma unroll
  for (int i = 0; i < 16; i++) psum += Tb[i];
  bool vpnz = (psum != 0.0f);

  float x = (float)ww, y = (float)hh;
  float cam0 = iKb[0]*x + iKb[1]*y + iKb[2];
  float cam1 = iKb[4]*x + iKb[5]*y + iKb[6];
  float cam2 = iKb[8]*x + iKb[9]*y + iKb[10];
  float qx = P[0][0]*cam0 + P[0][1]*cam1 + P[0][2]*cam2;
  float qy = P[1][0]*cam0 + P[1][1]*cam1 + P[1][2]*cam2;
  float qz = P[2][0]*cam0 + P[2][1]*cam1 + P[2][2]*cam2;
  float px3 = P[0][3], py3 = P[1][3], pz3 = P[2][3];
  bool interior = (hh >= 2 && hh <= HH-3 && ww >= 2 && ww <= WW-3);
  bool groupValid = interior && vpnz;

  int l4 = l * 4;
  const float* curp = curT + ((size_t)b * HWp + p) * CC + l4;
  F4 negCur[4];
  #pragma unroll
  for (int s4 = 0; s4 < 4; s4++) {
    F4 t; t.f = *(const float4*)(curp + s4 * 32);
    negCur[s4].h[0] = -t.h[0];
    negCur[s4].h[1] = -t.h[1];
  }
  const float* lookB = lookT + (size_t)b * HWp * CC;
  const float stepd = (20.0f - 0.1f) / 95.0f;

  float maxc = 0.0f;
  int cnt = 0;
  for (int dd = 0; dd < 24; dd++) {
    int d = wv * 24 + dd;
    float depth = 0.1f + (float)d * stepd;
    float s = 0.0f;
    if (groupValid) {
      float cxx = fmaf(depth, qx, px3);
      float cyy = fmaf(depth, qy, py3);
      float czz = fmaf(depth, qz, pz3);
      float r = __builtin_amdgcn_rcpf(czz + 1e-7f);
      float gx = cxx * r, gy = cyy * r;
      if (gx >= 2.0f && gx <= (float)(WW-2) && gy >= 2.0f && gy <= (float)(HH-2)) {
        float xf = floorf(gx), yf = floorf(gy);
        float wx = gx - xf, wy = gy - yf;
        int x0 = (int)xf, y0 = (int)yf;
        const float* bp0 = lookB + ((y0 * WW + x0) * CC + l4);
        const float* bp1 = bp0 + WW * CC;
        F4 v00[4], v10[4], v01[4], v11[4];
        #pragma unroll
        for (int s4 = 0; s4 < 4; s4++) {
          v00[s4].f = *(const float4*)(bp0 + s4 * 32);
          v10[s4].f = *(const float4*)(bp0 + s4 * 32 + CC);
          v01[s4].f = *(const float4*)(bp1 + s4 * 32);
          v11[s4].f = *(const float4*)(bp1 + s4 * 32 + CC);
        }
        float w11v = wx * wy;
        float w10v = wx - w11v, w01v = wy - w11v;
        float w00v = 1.0f - wx - wy + w11v;
        f32x2 W00 = {w00v, w00v}, W10 = {w10v, w10v};
        f32x2 W01 = {w01v, w01v}, W11 = {w11v, w11v};
        f32x2 accA = {0.f, 0.f}, accB = {0.f, 0.f};
        #pragma unroll
        for (int s4 = 0; s4 < 4; s4++) {
          #pragma unroll
          for (int hf = 0; hf < 2; hf++) {
            f32x2 t = negCur[s4].h[hf];
            t = __builtin_elementwise_fma(W00, v00[s4].h[hf], t);
            t = __builtin_elementwise_fma(W10, v10[s4].h[hf], t);
            t = __builtin_elementwise_fma(W01, v01[s4].h[hf], t);
            t = __builtin_elementwise_fma(W11, v11[s4].h[hf], t);
            f32x2 a = __builtin_elementwise_max(t, -t);
            if (s4 & 1) accB += a; else accA += a;
          }
        }
        f32x2 accT = accA + accB;
        s = accT.x + accT.y;
        s += __shfl_xor(s, 1, 8);
        s += __shfl_xor(s, 2, 8);
        s += __shfl_xor(s, 4, 8);
        s *= (1.0f / 128.0f / (1.0f + 1e-7f));
        cnt++;
        if (s > maxc) maxc = s;
      }
    }
    if (l == (d & 7)) costL[pix * 100 + d] = s;
  }
  if (l == 0) { cntL[wv][pix] = cnt; maxL[wv][pix] = maxc; }
  __syncthreads();

  int pix2 = tid >> 5, g = tid & 31;
  int p2 = blockIdx.x * 8 + pix2;
  float m0 = fmaxf(fmaxf(maxL[0][pix2], maxL[1][pix2]),
                   fmaxf(maxL[2][pix2], maxL[3][pix2]));
  int ct = cntL[0][pix2] + cntL[1][pix2] + cntL[2][pix2] + cntL[3][pix2];
  float confF = (ct == DD) ? 1.0f : 0.0f;
  float minv = 3.4e38f;
  int mind = 0x7fffffff;
  #pragma unroll
  for (int k = 0; k < 3; k++) {
    int d = g + 32 * k;
    float c = costL[pix2 * 100 + d];
    float filled = (c == 0.0f) ? m0 : c;
    float viz = (filled == 0.0f) ? 100.0f : filled;
    if (viz < minv) { minv = viz; mind = d; }
    fillL[pix2 * 96 + d] = (bf16_t)(filled * confF);
  }
  #pragma unroll
  for (int off = 1; off < 32; off <<= 1) {
    float ov = __shfl_xor(minv, off, 32);
    int   oi = __shfl_xor(mind, off, 32);
    if (ov < minv || (ov == minv && oi < mind)) { minv = ov; mind = oi; }
  }
  if (g == 0) {
    outLow[(size_t)b * HWp + p2] = 1.0f / (0.1f + (float)mind * stepd);
    outConf[(size_t)b * HWp + p2] = confF;
  }
  __syncthreads();
  const unsigned* fu = (const unsigned*)fillL;
  unsigned* cu = (unsigned*)(catT + ((size_t)b * HWp + p2) * CIN + CC);
  #pragma unroll
  for (int k = 0; k < 2; k++) {
    int idx = g + 32 * k;
    if (idx < 48) cu[idx] = fu[pix2 * 48 + idx];
  }
}

// ---------------------------------------------------------------------------
// Implicit-GEMM conv. Each wave: one 16-pixel tile x 64 out-channels (4 nt):
// one A-fragment feeds 4 MFMAs (A-traffic /4), 4 independent acc chains.
// Block's 4 waves: same nt-quad (B stream L1-shared), different pixel tiles.
// Grid (240,2) = 1920 waves.
// ---------------------------------------------------------------------------
__global__ __launch_bounds__(256) void k_conv(
    const bf16_t* __restrict__ catT, const bf16_t* __restrict__ wPack,
    const float* __restrict__ bias, float* __restrict__ out) {
  int wave = threadIdx.x >> 6;
  int lane = threadIdx.x & 63;
  int m16 = lane & 15, quad = lane >> 4;
  int tile = blockIdx.x * 4 + wave;
  int nt0 = blockIdx.y * 4;
  int P0 = tile * 16;
  int b = P0 / HWp;
  int rp = P0 % HWp;
  int h = rp / WW, w0 = rp % WW;

  f32x4 acc[4];
  #pragma unroll
  for (int j = 0; j < 4; j++) { f32x4 z = {0.f,0.f,0.f,0.f}; acc[j] = z; }

  const bf16_t* wbase = wPack + ((size_t)nt0 * NKC * 64 + (size_t)lane) * 8;

  #pragma unroll
  for (int tap = 0; tap < 9; tap++) {
    int dy = tap / 3 - 1, dx = tap % 3 - 1;
    int h2 = h + dy;
    int w2 = w0 + m16 + dx;
    bool valid = (h2 >= 0 && h2 < HH && w2 >= 0 && w2 < WW);
    const bf16_t* ap = catT + (ptrdiff_t)((b * HH + h2) * WW + w2) * CIN + quad * 8;
    #pragma unroll
    for (int sub = 0; sub < 7; sub++) {
      ABFrag a;
      if (valid) a.u = *(const uint4*)(ap + sub * 32);
      else       a.u = make_uint4(0u, 0u, 0u, 0u);
      int kc = tap * 7 + sub;
      const bf16_t* wp = wbase + (size_t)kc * 64 * 8;
      #pragma unroll
      for (int j = 0; j < 4; j++) {
        ABFrag bb;
        bb.u = *(const uint4*)(wp + (size_t)j * NKC * 64 * 8);
        acc[j] = __builtin_amdgcn_mfma_f32_16x16x32_bf16(a.v, bb.v, acc[j], 0, 0, 0);
      }
    }
  }
  // C/D layout: n = lane&15, m = quad*4 + r
  #pragma unroll
  for (int j = 0; j < 4; j++) {
    int co = (nt0 + j) * 16 + m16;
    float bi = bias[co];
    #pragma unroll
    for (int r = 0; r < 4; r++) {
      int wloc = w0 + quad * 4 + r;
      float v = acc[j][r] + bi;
      v = v > 0.0f ? v : 0.0f;
      out[(((size_t)b * CC + co) * HH + h) * WW + wloc] = v;
    }
  }
}

// ---------------------------------------------------------------------------
extern "C" void kernel_launch(void* const* d_in, const int* in_sizes, int n_in,
                              void* d_out, int out_size, void* d_ws, size_t ws_size,
                              hipStream_t stream) {
  const float* cur   = (const float*)d_in[0];
  const float* look  = (const float*)d_in[1];
  const float* poses = (const float*)d_in[2];
  const float* Km    = (const float*)d_in[3];
  const float* iK    = (const float*)d_in[4];
  const float* cw    = (const float*)d_in[5];
  const float* cb    = (const float*)d_in[6];

  float* out     = (float*)d_out;
  float* outLow  = out + (size_t)BB * CC * HWp;
  float* outConf = outLow + (size_t)BB * HWp;

  char* ws = (char*)d_ws;
  float*  curT  = (float*)ws;                                   // 7,864,320 B
  float*  lookT = (float*)(ws + 7864320);                       // 7,864,320 B
  bf16_t* catT  = (bf16_t*)(ws + 2 * 7864320);                  // 6,881,280 B
  bf16_t* wPack = (bf16_t*)(ws + 2 * 7864320 + 6881280);        //   516,096 B

  k_prep<<<dim3(120, 5), 256, 0, stream>>>(cur, look, cw, curT, lookT, catT, wPack);
  k_cost<<<dim3(960, 2), 256, 0, stream>>>(curT, lookT, poses, Km, iK,
                                           catT, outLow, outConf);
  k_conv<<<dim3(240, 2), 256, 0, stream>>>(catT, wPack, cb, out);
}

// Round 5
// 158.446 us; speedup vs baseline: 1.3471x; 1.2859x over previous
//
#include <hip/hip_runtime.h>
#include <hip/hip_bf16.h>

#define BB 2
#define CC 128
#define HH 48
#define WW 160
#define DD 96
#define HWp (HH*WW)     // 7680
#define CIN 224         // C + D
#define NKC 63          // 2016 / 32 K-chunks

typedef __bf16 bf16_t;
typedef __bf16 bf16x8 __attribute__((ext_vector_type(8)));
typedef float  f32x4  __attribute__((ext_vector_type(4)));
typedef float  f32x2  __attribute__((ext_vector_type(2)));

union ABFrag { uint4 u; bf16x8 v; };
union PackW  { bf16_t h[8]; uint4 u; };
union F4     { float4 f; f32x2 h[2]; };

// ---------------------------------------------------------------------------
// Prep: y = 0..3 -> NCHW->channel-last transpose (cur/look x batch);
//       y = 4   -> conv_w pack into MFMA B-fragment order (grid-stride).
// ---------------------------------------------------------------------------
__global__ __launch_bounds__(256) void k_prep(
    const float* __restrict__ cur, const float* __restrict__ look,
    const float* __restrict__ cw,
    float* __restrict__ curT, float* __restrict__ lookT,
    bf16_t* __restrict__ catT, bf16_t* __restrict__ wPack) {
  int z = blockIdx.y;
  if (z < 4) {
    __shared__ float tile[CC * 65];
    int bIdx = z & 1;
    bool isCur = (z < 2);
    const float* src = (isCur ? cur : look) + (size_t)bIdx * CC * HWp;
    int p0 = blockIdx.x * 64;
    int tid = threadIdx.x;
    int px = tid & 63, cb = tid >> 6;
    #pragma unroll
    for (int k = 0; k < 32; k++) {
      int c = k * 4 + cb;
      tile[c * 65 + px] = src[(size_t)c * HWp + p0 + px];
    }
    __syncthreads();
    int ci = tid & 127, pb = tid >> 7;
    #pragma unroll
    for (int k = 0; k < 32; k++) {
      int pp = k * 2 + pb;
      float v = tile[ci * 65 + pp];
      size_t pix = (size_t)bIdx * HWp + p0 + pp;
      if (isCur) {
        curT[pix * CC + ci] = v;
        catT[pix * CIN + ci] = (bf16_t)v;
      } else {
        lookT[pix * CC + ci] = v;
      }
    }
  } else {
    for (int t = blockIdx.x * 256 + threadIdx.x; t < 8 * NKC * 64; t += 120 * 256) {
      int lane = t & 63;
      int kc = (t >> 6) % NKC;
      int nt = t / (NKC * 64);
      int co = nt * 16 + (lane & 15);
      int kbase = kc * 32 + (lane >> 4) * 8;
      PackW tmp;
      #pragma unroll
      for (int j = 0; j < 8; j++) {
        int kk = kbase + j;
        int tap = kk / 224, ci2 = kk % 224;
        int ky = tap / 3, kx = tap % 3;
        tmp.h[j] = (bf16_t)cw[(((size_t)co * 224 + ci2) * 3 + ky) * 3 + kx];
      }
      *(uint4*)(wPack + (size_t)t * 8) = tmp.u;
    }
  }
}

// ---------------------------------------------------------------------------
// Fused plane-sweep cost with DEPTH-COHERENT CORNER REUSE: the bilinear cell
// (x0,y0) changes only ~10-20 times over 96 depths, so the 16 corner float4s
// stay in registers and reload only on cell change (per-pixel-group exec
// mask). Block = 256 thr = 4 waves over the SAME 8 pixels; wave wv covers
// 24 depths; 8 lanes/pixel, 16 ch/lane, packed-fp32 math.
// ---------------------------------------------------------------------------
__global__ __launch_bounds__(256) void k_cost(
    const float* __restrict__ curT, const float* __restrict__ lookT,
    const float* __restrict__ poses, const float* __restrict__ Kmat,
    const float* __restrict__ invK,
    bf16_t* __restrict__ catT, float* __restrict__ outLow,
    float* __restrict__ outConf) {
  __shared__ float costL[8 * 100];
  __shared__ float maxL[4][8];
  __shared__ int   cntL[4][8];
  __shared__ __align__(4) bf16_t fillL[8 * 96];

  int tid = threadIdx.x;
  int b = blockIdx.y;
  int wv = tid >> 6;
  int lane = tid & 63;
  int pix = lane >> 3;
  int l = lane & 7;
  int p = blockIdx.x * 8 + pix;
  int hh = p / WW, ww = p % WW;

  const float* Kb  = Kmat + b * 16;
  const float* Tb  = poses + b * 16;   // F = 1
  const float* iKb = invK + b * 16;
  float P[3][4];
  #pragma unroll
  for (int i = 0; i < 3; i++)
    #pragma unroll
    for (int j = 0; j < 4; j++)
      P[i][j] = Kb[i*4+0]*Tb[0*4+j] + Kb[i*4+1]*Tb[1*4+j]
              + Kb[i*4+2]*Tb[2*4+j] + Kb[i*4+3]*Tb[3*4+j];
  float psum = 0.0f;
  #pragma unroll
  for (int i = 0; i < 16; i++) psum += Tb[i];
  bool vpnz = (psum != 0.0f);

  float x = (float)ww, y = (float)hh;
  float cam0 = iKb[0]*x + iKb[1]*y + iKb[2];
  float cam1 = iKb[4]*x + iKb[5]*y + iKb[6];
  float cam2 = iKb[8]*x + iKb[9]*y + iKb[10];
  float qx = P[0][0]*cam0 + P[0][1]*cam1 + P[0][2]*cam2;
  float qy = P[1][0]*cam0 + P[1][1]*cam1 + P[1][2]*cam2;
  float qz = P[2][0]*cam0 + P[2][1]*cam1 + P[2][2]*cam2;
  float px3 = P[0][3], py3 = P[1][3], pz3 = P[2][3];
  bool interior = (hh >= 2 && hh <= HH-3 && ww >= 2 && ww <= WW-3);
  bool groupValid = interior && vpnz;

  int l4 = l * 4;
  const float* curp = curT + ((size_t)b * HWp + p) * CC + l4;
  F4 negCur[4];
  #pragma unroll
  for (int s4 = 0; s4 < 4; s4++) {
    F4 t; t.f = *(const float4*)(curp + s4 * 32);
    negCur[s4].h[0] = -t.h[0];
    negCur[s4].h[1] = -t.h[1];
  }
  const float* lookB = lookT + (size_t)b * HWp * CC;
  const float stepd = (20.0f - 0.1f) / 95.0f;

  float maxc = 0.0f;
  int cnt = 0;
  int prevCell = -1;
  float x0f = 0.0f, y0f = 0.0f;
  F4 v00[4], v10[4], v01[4], v11[4];
  #pragma unroll
  for (int s4 = 0; s4 < 4; s4++) {
    v00[s4].f = make_float4(0.f,0.f,0.f,0.f);
    v10[s4].f = make_float4(0.f,0.f,0.f,0.f);
    v01[s4].f = make_float4(0.f,0.f,0.f,0.f);
    v11[s4].f = make_float4(0.f,0.f,0.f,0.f);
  }

  for (int dd = 0; dd < 24; dd++) {
    int d = wv * 24 + dd;
    float depth = 0.1f + (float)d * stepd;
    float s = 0.0f;
    if (groupValid) {
      float cxx = fmaf(depth, qx, px3);
      float cyy = fmaf(depth, qy, py3);
      float czz = fmaf(depth, qz, pz3);
      float r = __builtin_amdgcn_rcpf(czz + 1e-7f);
      float gx = cxx * r, gy = cyy * r;
      if (gx >= 2.0f && gx <= (float)(WW-2) && gy >= 2.0f && gy <= (float)(HH-2)) {
        float xf = floorf(gx), yf = floorf(gy);
        int x0 = (int)xf, y0 = (int)yf;
        int cell = y0 * WW + x0;
        if (cell != prevCell) {
          prevCell = cell; x0f = xf; y0f = yf;
          const float* bp0 = lookB + ((size_t)cell * CC + l4);
          const float* bp1 = bp0 + WW * CC;
          #pragma unroll
          for (int s4 = 0; s4 < 4; s4++) {
            v00[s4].f = *(const float4*)(bp0 + s4 * 32);
            v10[s4].f = *(const float4*)(bp0 + s4 * 32 + CC);
            v01[s4].f = *(const float4*)(bp1 + s4 * 32);
            v11[s4].f = *(const float4*)(bp1 + s4 * 32 + CC);
          }
        }
        float wx = gx - x0f, wy = gy - y0f;
        float w11v = wx * wy;
        float w10v = wx - w11v, w01v = wy - w11v;
        float w00v = 1.0f - wx - wy + w11v;
        f32x2 W00 = {w00v, w00v}, W10 = {w10v, w10v};
        f32x2 W01 = {w01v, w01v}, W11 = {w11v, w11v};
        f32x2 accA = {0.f, 0.f}, accB = {0.f, 0.f};
        #pragma unroll
        for (int s4 = 0; s4 < 4; s4++) {
          #pragma unroll
          for (int hf = 0; hf < 2; hf++) {
            f32x2 t = negCur[s4].h[hf];
            t = __builtin_elementwise_fma(W00, v00[s4].h[hf], t);
            t = __builtin_elementwise_fma(W10, v10[s4].h[hf], t);
            t = __builtin_elementwise_fma(W01, v01[s4].h[hf], t);
            t = __builtin_elementwise_fma(W11, v11[s4].h[hf], t);
            f32x2 a = __builtin_elementwise_max(t, -t);
            if (s4 & 1) accB += a; else accA += a;
          }
        }
        f32x2 accT = accA + accB;
        s = accT.x + accT.y;
        s += __shfl_xor(s, 1, 8);
        s += __shfl_xor(s, 2, 8);
        s += __shfl_xor(s, 4, 8);
        s *= (1.0f / 128.0f / (1.0f + 1e-7f));
        cnt++;
        if (s > maxc) maxc = s;
      }
    }
    if (l == (d & 7)) costL[pix * 100 + d] = s;
  }
  if (l == 0) { cntL[wv][pix] = cnt; maxL[wv][pix] = maxc; }
  __syncthreads();

  int pix2 = tid >> 5, g = tid & 31;
  int p2 = blockIdx.x * 8 + pix2;
  float m0 = fmaxf(fmaxf(maxL[0][pix2], maxL[1][pix2]),
                   fmaxf(maxL[2][pix2], maxL[3][pix2]));
  int ct = cntL[0][pix2] + cntL[1][pix2] + cntL[2][pix2] + cntL[3][pix2];
  float confF = (ct == DD) ? 1.0f : 0.0f;
  float minv = 3.4e38f;
  int mind = 0x7fffffff;
  #pragma unroll
  for (int k = 0; k < 3; k++) {
    int d = g + 32 * k;
    float c = costL[pix2 * 100 + d];
    float filled = (c == 0.0f) ? m0 : c;
    float viz = (filled == 0.0f) ? 100.0f : filled;
    if (viz < minv) { minv = viz; mind = d; }
    fillL[pix2 * 96 + d] = (bf16_t)(filled * confF);
  }
  #pragma unroll
  for (int off = 1; off < 32; off <<= 1) {
    float ov = __shfl_xor(minv, off, 32);
    int   oi = __shfl_xor(mind, off, 32);
    if (ov < minv || (ov == minv && oi < mind)) { minv = ov; mind = oi; }
  }
  if (g == 0) {
    outLow[(size_t)b * HWp + p2] = 1.0f / (0.1f + (float)mind * stepd);
    outConf[(size_t)b * HWp + p2] = confF;
  }
  __syncthreads();
  const unsigned* fu = (const unsigned*)fillL;
  unsigned* cu = (unsigned*)(catT + ((size_t)b * HWp + p2) * CIN + CC);
  #pragma unroll
  for (int k = 0; k < 2; k++) {
    int idx = g + 32 * k;
    if (idx < 48) cu[idx] = fu[pix2 * 48 + idx];
  }
}

// ---------------------------------------------------------------------------
// Implicit-GEMM conv (R2 shape — best residual). Each wave: one 16-pixel
// tile x 32 out-channels (2 nt). Block's 4 waves share the SAME nt-pair
// (B stream L1-shared), different pixel tiles. 3840 waves (15/CU).
// ---------------------------------------------------------------------------
__global__ __launch_bounds__(256) void k_conv(
    const bf16_t* __restrict__ catT, const bf16_t* __restrict__ wPack,
    const float* __restrict__ bias, float* __restrict__ out) {
  int wave = threadIdx.x >> 6;
  int lane = threadIdx.x & 63;
  int m16 = lane & 15, quad = lane >> 4;
  int tile = blockIdx.x * 4 + wave;
  int nt0 = blockIdx.y * 2;
  int P0 = tile * 16;
  int b = P0 / HWp;
  int rp = P0 % HWp;
  int h = rp / WW, w0 = rp % WW;

  f32x4 acc[2];
  #pragma unroll
  for (int j = 0; j < 2; j++) { f32x4 z = {0.f,0.f,0.f,0.f}; acc[j] = z; }

  #pragma unroll
  for (int tap = 0; tap < 9; tap++) {
    int dy = tap / 3 - 1, dx = tap % 3 - 1;
    int h2 = h + dy;
    int w2 = w0 + m16 + dx;
    bool valid = (h2 >= 0 && h2 < HH && w2 >= 0 && w2 < WW);
    const bf16_t* ap = catT + (ptrdiff_t)((b * HH + h2) * WW + w2) * CIN + quad * 8;
    #pragma unroll
    for (int sub = 0; sub < 7; sub++) {
      ABFrag a;
      if (valid) a.u = *(const uint4*)(ap + sub * 32);
      else       a.u = make_uint4(0u, 0u, 0u, 0u);
      int kc = tap * 7 + sub;
      #pragma unroll
      for (int j = 0; j < 2; j++) {
        ABFrag bb;
        bb.u = *(const uint4*)(wPack + (((size_t)(nt0 + j) * NKC + kc) * 64 + lane) * 8);
        acc[j] = __builtin_amdgcn_mfma_f32_16x16x32_bf16(a.v, bb.v, acc[j], 0, 0, 0);
      }
    }
  }
  #pragma unroll
  for (int j = 0; j < 2; j++) {
    int co = (nt0 + j) * 16 + m16;
    float bi = bias[co];
    #pragma unroll
    for (int r = 0; r < 4; r++) {
      int wloc = w0 + quad * 4 + r;
      float v = acc[j][r] + bi;
      v = v > 0.0f ? v : 0.0f;
      out[(((size_t)b * CC + co) * HH + h) * WW + wloc] = v;
    }
  }
}

// ---------------------------------------------------------------------------
extern "C" void kernel_launch(void* const* d_in, const int* in_sizes, int n_in,
                              void* d_out, int out_size, void* d_ws, size_t ws_size,
                              hipStream_t stream) {
  const float* cur   = (const float*)d_in[0];
  const float* look  = (const float*)d_in[1];
  const float* poses = (const float*)d_in[2];
  const float* Km    = (const float*)d_in[3];
  const float* iK    = (const float*)d_in[4];
  const float* cw    = (const float*)d_in[5];
  const float* cb    = (const float*)d_in[6];

  float* out     = (float*)d_out;
  float* outLow  = out + (size_t)BB * CC * HWp;
  float* outConf = outLow + (size_t)BB * HWp;

  char* ws = (char*)d_ws;
  float*  curT  = (float*)ws;                                   // 7,864,320 B
  float*  lookT = (float*)(ws + 7864320);                       // 7,864,320 B
  bf16_t* catT  = (bf16_t*)(ws + 2 * 7864320);                  // 6,881,280 B
  bf16_t* wPack = (bf16_t*)(ws + 2 * 7864320 + 6881280);        //   516,096 B

  k_prep<<<dim3(120, 5), 256, 0, stream>>>(cur, look, cw, curT, lookT, catT, wPack);
  k_cost<<<dim3(960, 2), 256, 0, stream>>>(curT, lookT, poses, Km, iK,
                                           catT, outLow, outConf);
  k_conv<<<dim3(240, 4), 256, 0, stream>>>(catT, wPack, cb, out);
}